// Round 16
// baseline (120.995 us; speedup 1.0000x reference)
//
#include <hip/hip_runtime.h>

typedef float v2f __attribute__((ext_vector_type(2)));

#define W_IMG 512
#define H_IMG 512
#define PLANES 96                  // 32 * 3
#define NPIX 25165824.0            // 96 * 512 * 512

#define SWIDE 128                  // output cols per wave (2 per lane)
#define SH  32                     // output rows per wave (r15 A/B: 64 -> 32, 2x waves)
#define NROWS (SH + 10)            // 42 streamed input rows
#define NQUAD 36                   // staged col-quads per row (144 cols, pad 8 left)
#define NPRS  72                   // staged float4 pair-slots per row
#define XS (W_IMG / SWIDE)         // 4 strips
#define YB (H_IMG / SH)            // 16 bands
#define WPB 2                      // waves per block

__global__ void ssim_zero(double* acc) {
    if (threadIdx.x < PLANES) acc[threadIdx.x] = 0.0;
}

__global__ void ssim_final(const double* __restrict__ acc, float* __restrict__ out) {
    const int L = threadIdx.x;   // one wave
    double s = (L < PLANES) ? acc[L] : 0.0;
    if (L + 64 < PLANES) s += acc[L + 64];
    #pragma unroll
    for (int off = 32; off > 0; off >>= 1) s += __shfl_down(s, off, 64);
    if (L == 0) out[0] = (float)(1.0 - s / NPIX);
}

// packed fp32 VOP3P (r9-proven syntax; fma ties the accumulator)
__device__ __forceinline__ v2f pk_add2(v2f a, v2f b) {
    v2f d; asm("v_pk_add_f32 %0, %1, %2" : "=v"(d) : "v"(a), "v"(b)); return d;
}
__device__ __forceinline__ v2f pk_mul2(v2f a, v2f b) {
    v2f d; asm("v_pk_mul_f32 %0, %1, %2" : "=v"(d) : "v"(a), "v"(b)); return d;
}
__device__ __forceinline__ v2f pk_fma2(v2f a, v2f b, v2f c) {
    asm("v_pk_fma_f32 %0, %1, %2, %0" : "+v"(c) : "v"(a), "v"(b)); return c;
}

__global__ __launch_bounds__(128, 2)
void ssim_main(const float* __restrict__ img1,
               const float* __restrict__ img2,
               double* __restrict__ acc)
{
    // normalized 11-tap Gaussian, sigma=1.5 (matches reference _create_window)
    constexpr float G0=0.00102838f, G1=0.00759875f, G2c=0.03600077f,
                    G3=0.10936070f, G4=0.21300540f, G5=0.26601180f,
                    G6=0.21300540f, G7=0.10936070f, G8=0.03600077f,
                    G9=0.00759875f, G10=0.00102838f;
    constexpr float K_C1 = 0.0001f;
    constexpr float K_C2 = 0.0009f;

    // H coefficient pair-tables (window parity is lane-uniform):
    // px0 uses pairs p=0..5 (taps -1..10), px1 uses pairs p=1..6 (taps 0..11)
    const v2f Gp1[6] = { {0.f,G0}, {G1,G2c}, {G3,G4}, {G5,G6}, {G7,G8}, {G9,G10} };
    const v2f Gp2[6] = { {G0,G1}, {G2c,G3}, {G4,G5}, {G6,G7}, {G8,G9}, {G10,0.f} };
    const v2f GV[11] = { {G0,G0},{G1,G1},{G2c,G2c},{G3,G3},{G4,G4},{G5,G5},
                         {G6,G6},{G7,G7},{G8,G8},{G9,G9},{G10,G10} };

    // per-wave double-buffered row: pair-slot = {a0,a1,b0,b1}
    __shared__ __align__(16) float4 sp[WPB][2][NPRS];

    const int tid = threadIdx.x;
    const int wv  = tid >> 6;
    const int L   = tid & 63;
    const int wid = blockIdx.x * WPB + wv;     // 0..63 per plane
    const int c0  = (wid & (XS - 1)) * SWIDE;
    const int r0  = (wid >> 2) * SH;
    const int plane = blockIdx.y;
    const size_t pofs = (size_t)plane * (H_IMG * W_IMG);
    const float* __restrict__ p1 = img1 + pofs;
    const float* __restrict__ p2 = img2 + pofs;

    // staging: lane < 36 owns quad q=L, global cols c0-8+4L .. +3 (never straddles)
    const int gq  = c0 - 8 + 4 * L;
    const bool qok = (L < NQUAD) && (gq >= 0) && (gq <= W_IMG - 4);
    const bool sth = (L < NQUAD);

    float4 qa = make_float4(0.f,0.f,0.f,0.f), qb = qa;
    auto LOADROW = [&](int s) {
        qa = make_float4(0.f,0.f,0.f,0.f); qb = qa;
        const int gr = r0 - 5 + s;
        if (qok && (unsigned)gr < (unsigned)H_IMG) {
            const int off = gr * W_IMG + gq;
            __builtin_memcpy(&qa, p1 + off, 16);
            __builtin_memcpy(&qb, p2 + off, 16);
        }
    };
    auto STORE = [&](int buf) {
        if (sth) {
            sp[wv][buf][2*L]   = make_float4(qa.x, qa.y, qb.x, qb.y);
            sp[wv][buf][2*L+1] = make_float4(qa.z, qa.w, qb.z, qb.w);
        }
    };

    const float4* __restrict__ wb0 = &sp[wv][0][L + 1];
    const float4* __restrict__ wb1 = &sp[wv][1][L + 1];

    // rings: 4 maps x 11 rows, each slot = (px0, px1)
    v2f ring_m1[11], ring_m2[11], ring_ab[11], ring_s2[11];
    float lsum = 0.f;
    const v2f z2 = {0.f, 0.f};

    // prologue: row 0 staged into buf 0, its window prefetched; row 1 in regs
    LOADROW(0); STORE(0); LOADROW(1);
    float4 W[7];
    #pragma unroll
    for (int p = 0; p < 7; ++p) W[p] = wb0[p];

    int cur = 0;
    #pragma unroll 1
    for (int sb = 0; sb < 44; sb += 11) {
        #pragma unroll
        for (int j = 0; j < 11; ++j) {
            const int s = sb + j;                 // streamed row; ring slot = j

            if (s + 1 < NROWS) STORE(cur ^ 1);    // row s+1 from regs
            if (s + 2 < NROWS) LOADROW(s + 2);    // prefetch row s+2 (global)

            // ---- H: packed 4-map conv on row s, operating on prefetched W ----
            if (s < NROWS) {
                v2f m1a=z2, m2a=z2, aba=z2, s2a=z2;   // px0
                v2f m1b=z2, m2b=z2, abb=z2, s2b=z2;   // px1
                #pragma unroll
                for (int p = 0; p < 7; ++p) {
                    const float4 P = W[p];
                    const v2f ap = {P.x, P.y};
                    const v2f bp = {P.z, P.w};
                    const v2f spp = pk_add2(ap, bp);
                    if (p < 6) {
                        const v2f g = Gp1[p];
                        m1a = pk_fma2(g, ap, m1a);
                        m2a = pk_fma2(g, bp, m2a);
                        const v2f t1 = pk_mul2(g, ap);
                        aba = pk_fma2(t1, bp, aba);
                        const v2f t2 = pk_mul2(g, spp);
                        s2a = pk_fma2(t2, spp, s2a);
                    }
                    if (p > 0) {
                        const v2f g = Gp2[p - 1];
                        m1b = pk_fma2(g, ap, m1b);
                        m2b = pk_fma2(g, bp, m2b);
                        const v2f t1 = pk_mul2(g, ap);
                        abb = pk_fma2(t1, bp, abb);
                        const v2f t2 = pk_mul2(g, spp);
                        s2b = pk_fma2(t2, spp, s2b);
                    }
                }
                ring_m1[j] = (v2f){ m1a.x + m1a.y, m1b.x + m1b.y };
                ring_m2[j] = (v2f){ m2a.x + m2a.y, m2b.x + m2b.y };
                ring_ab[j] = (v2f){ aba.x + aba.y, abb.x + abb.y };
                ring_s2[j] = (v2f){ s2a.x + s2a.y, s2b.x + s2b.y };
            }

            // ---- prefetch row s+1's window (just stored into buf cur^1);
            //      ds_read latency hides under V + epilogue below ----
            float4 Wn[7];
            if (s + 1 < NROWS) {
                const float4* __restrict__ wbn = (cur ^ 1) ? wb1 : wb0;
                #pragma unroll
                for (int p = 0; p < 7; ++p) Wn[p] = wbn[p];
            }

            // ---- V: packed 11-tap over ring + SSIM for output row s-10 ----
            if (s >= 10 && s < NROWS) {
                v2f M1=z2, M2=z2, AB=z2, S2=z2;
                #pragma unroll
                for (int k = 0; k < 11; ++k) {
                    const int sl = (j + 1 + k) % 11;   // compile-time
                    M1 = pk_fma2(GV[k], ring_m1[sl], M1);
                    M2 = pk_fma2(GV[k], ring_m2[sl], M2);
                    AB = pk_fma2(GV[k], ring_ab[sl], AB);
                    S2 = pk_fma2(GV[k], ring_s2[sl], S2);
                }
                #pragma unroll
                for (int h = 0; h < 2; ++h) {
                    const float u1 = h ? M1.y : M1.x;
                    const float u2 = h ? M2.y : M2.x;
                    const float eab = h ? AB.y : AB.x;
                    const float es2 = h ? S2.y : S2.x;
                    const float mu12 = u1 * u2;
                    const float musq = fmaf(u1, u1, u2 * u2);
                    const float sig12 = eab - mu12;
                    const float sigsum = fmaxf(fmaf(-2.f, eab, es2) - musq, 0.f);
                    const float num = fmaf(2.f, mu12, K_C1) * fmaf(2.f, sig12, K_C2);
                    const float den = (musq + K_C1) * (sigsum + K_C2);
                    lsum = fmaf(num, __builtin_amdgcn_rcpf(den), lsum);
                }
            }

            // commit prefetched window (register renames in unrolled code)
            #pragma unroll
            for (int p = 0; p < 7; ++p) W[p] = Wn[p];
            cur ^= 1;
        }
    }

    // ---- wave reduce -> one atomic per wave into per-plane slot ----
    #pragma unroll
    for (int off = 32; off > 0; off >>= 1)
        lsum += __shfl_down(lsum, off, 64);
    if (L == 0)
        atomicAdd(&acc[plane], (double)lsum);
}

extern "C" void kernel_launch(void* const* d_in, const int* in_sizes, int n_in,
                              void* d_out, int out_size, void* d_ws, size_t ws_size,
                              hipStream_t stream) {
    const float* img1 = (const float*)d_in[0];
    const float* img2 = (const float*)d_in[1];
    float* out  = (float*)d_out;
    double* acc = (double*)d_ws;   // 96 per-plane accumulators

    ssim_zero<<<dim3(1), dim3(128), 0, stream>>>(acc);
    ssim_main<<<dim3(XS * YB / WPB, PLANES), dim3(64 * WPB), 0, stream>>>(img1, img2, acc);
    ssim_final<<<dim3(1), dim3(64), 0, stream>>>(acc, out);
}

// Round 17
// 113.703 us; speedup vs baseline: 1.0641x; 1.0641x over previous
//
#include <hip/hip_runtime.h>

typedef float v2f __attribute__((ext_vector_type(2)));

#define W_IMG 512
#define H_IMG 512
#define PLANES 96                  // 32 * 3
#define NPIX 25165824.0            // 96 * 512 * 512

#define SWIDE 128                  // output cols per wave (2 per lane)
#define SH  64                     // output rows per wave
#define NROWS (SH + 10)            // 74 streamed input rows
#define NQUAD 36                   // staged col-quads per row (144 cols, pad 8 left)
#define NPRS  72                   // staged float4 pair-slots per row
#define XS (W_IMG / SWIDE)         // 4 strips
#define YB (H_IMG / SH)            // 8 bands
#define WPB 2                      // waves per block

__global__ void ssim_zero(double* acc) {
    if (threadIdx.x < PLANES) acc[threadIdx.x] = 0.0;
}

__global__ void ssim_final(const double* __restrict__ acc, float* __restrict__ out) {
    const int L = threadIdx.x;   // one wave
    double s = (L < PLANES) ? acc[L] : 0.0;
    if (L + 64 < PLANES) s += acc[L + 64];
    #pragma unroll
    for (int off = 32; off > 0; off >>= 1) s += __shfl_down(s, off, 64);
    if (L == 0) out[0] = (float)(1.0 - s / NPIX);
}

// packed fp32 VOP3P (r9-proven syntax; fma ties the accumulator)
__device__ __forceinline__ v2f pk_add2(v2f a, v2f b) {
    v2f d; asm("v_pk_add_f32 %0, %1, %2" : "=v"(d) : "v"(a), "v"(b)); return d;
}
__device__ __forceinline__ v2f pk_mul2(v2f a, v2f b) {
    v2f d; asm("v_pk_mul_f32 %0, %1, %2" : "=v"(d) : "v"(a), "v"(b)); return d;
}
__device__ __forceinline__ v2f pk_fma2(v2f a, v2f b, v2f c) {
    asm("v_pk_fma_f32 %0, %1, %2, %0" : "+v"(c) : "v"(a), "v"(b)); return c;
}

__global__ __launch_bounds__(128, 2)
void ssim_main(const float* __restrict__ img1,
               const float* __restrict__ img2,
               double* __restrict__ acc)
{
    // normalized 11-tap Gaussian, sigma=1.5 (matches reference _create_window)
    constexpr float G0=0.00102838f, G1=0.00759875f, G2c=0.03600077f,
                    G3=0.10936070f, G4=0.21300540f, G5=0.26601180f,
                    G6=0.21300540f, G7=0.10936070f, G8=0.03600077f,
                    G9=0.00759875f, G10=0.00102838f;
    constexpr float K_C1 = 0.0001f;
    constexpr float K_C2 = 0.0009f;

    // H coefficient pair-tables (window parity is lane-uniform):
    // px0 uses pairs p=0..5 (taps -1..10), px1 uses pairs p=1..6 (taps 0..11)
    const v2f Gp1[6] = { {0.f,G0}, {G1,G2c}, {G3,G4}, {G5,G6}, {G7,G8}, {G9,G10} };
    const v2f Gp2[6] = { {G0,G1}, {G2c,G3}, {G4,G5}, {G6,G7}, {G8,G9}, {G10,0.f} };
    const v2f GV[11] = { {G0,G0},{G1,G1},{G2c,G2c},{G3,G3},{G4,G4},{G5,G5},
                         {G6,G6},{G7,G7},{G8,G8},{G9,G9},{G10,G10} };

    // per-wave double-buffered row: pair-slot = {a0,a1,b0,b1}
    __shared__ __align__(16) float4 sp[WPB][2][NPRS];

    const int tid = threadIdx.x;
    const int wv  = tid >> 6;
    const int L   = tid & 63;
    const int wid = blockIdx.x * WPB + wv;     // 0..31 per plane
    const int c0  = (wid & (XS - 1)) * SWIDE;
    const int r0  = (wid >> 2) * SH;
    const int plane = blockIdx.y;
    const size_t pofs = (size_t)plane * (H_IMG * W_IMG);
    const float* __restrict__ p1 = img1 + pofs;
    const float* __restrict__ p2 = img2 + pofs;

    // staging: lane < 36 owns quad q=L, global cols c0-8+4L .. +3 (never straddles)
    const int gq  = c0 - 8 + 4 * L;
    const bool qok = (L < NQUAD) && (gq >= 0) && (gq <= W_IMG - 4);
    const bool sth = (L < NQUAD);

    float4 qa = make_float4(0.f,0.f,0.f,0.f), qb = qa;
    auto LOADROW = [&](int s) {
        qa = make_float4(0.f,0.f,0.f,0.f); qb = qa;
        const int gr = r0 - 5 + s;
        if (qok && (unsigned)gr < (unsigned)H_IMG) {
            const int off = gr * W_IMG + gq;
            __builtin_memcpy(&qa, p1 + off, 16);
            __builtin_memcpy(&qb, p2 + off, 16);
        }
    };
    auto STORE = [&](int buf) {
        if (sth) {
            sp[wv][buf][2*L]   = make_float4(qa.x, qa.y, qb.x, qb.y);
            sp[wv][buf][2*L+1] = make_float4(qa.z, qa.w, qb.z, qb.w);
        }
    };

    const float4* __restrict__ wb0 = &sp[wv][0][L + 1];
    const float4* __restrict__ wb1 = &sp[wv][1][L + 1];

    // rings: 4 maps x 11 rows, each slot = (px0, px1)
    v2f ring_m1[11], ring_m2[11], ring_ab[11], ring_s2[11];
    float lsum = 0.f;
    const v2f z2 = {0.f, 0.f};

    // prologue: row 0 staged into buf 0, its window prefetched; row 1 in regs
    LOADROW(0); STORE(0); LOADROW(1);
    float4 W[7];
    #pragma unroll
    for (int p = 0; p < 7; ++p) W[p] = wb0[p];

    int cur = 0;
    #pragma unroll 1
    for (int sb = 0; sb < 77; sb += 11) {
        #pragma unroll
        for (int j = 0; j < 11; ++j) {
            const int s = sb + j;                 // streamed row; ring slot = j

            if (s + 1 < NROWS) STORE(cur ^ 1);    // row s+1 from regs
            if (s + 2 < NROWS) LOADROW(s + 2);    // prefetch row s+2 (global)

            // ---- H: packed 4-map conv on row s, operating on prefetched W ----
            if (s < NROWS) {
                v2f m1a=z2, m2a=z2, aba=z2, s2a=z2;   // px0
                v2f m1b=z2, m2b=z2, abb=z2, s2b=z2;   // px1
                #pragma unroll
                for (int p = 0; p < 7; ++p) {
                    const float4 P = W[p];
                    const v2f ap = {P.x, P.y};
                    const v2f bp = {P.z, P.w};
                    const v2f spp = pk_add2(ap, bp);
                    if (p < 6) {
                        const v2f g = Gp1[p];
                        m1a = pk_fma2(g, ap, m1a);
                        m2a = pk_fma2(g, bp, m2a);
                        const v2f t1 = pk_mul2(g, ap);
                        aba = pk_fma2(t1, bp, aba);
                        const v2f t2 = pk_mul2(g, spp);
                        s2a = pk_fma2(t2, spp, s2a);
                    }
                    if (p > 0) {
                        const v2f g = Gp2[p - 1];
                        m1b = pk_fma2(g, ap, m1b);
                        m2b = pk_fma2(g, bp, m2b);
                        const v2f t1 = pk_mul2(g, ap);
                        abb = pk_fma2(t1, bp, abb);
                        const v2f t2 = pk_mul2(g, spp);
                        s2b = pk_fma2(t2, spp, s2b);
                    }
                }
                ring_m1[j] = (v2f){ m1a.x + m1a.y, m1b.x + m1b.y };
                ring_m2[j] = (v2f){ m2a.x + m2a.y, m2b.x + m2b.y };
                ring_ab[j] = (v2f){ aba.x + aba.y, abb.x + abb.y };
                ring_s2[j] = (v2f){ s2a.x + s2a.y, s2b.x + s2b.y };
            }

            // ---- prefetch row s+1's window (just stored into buf cur^1);
            //      ds_read latency hides under V + epilogue below ----
            float4 Wn[7];
            if (s + 1 < NROWS) {
                const float4* __restrict__ wbn = (cur ^ 1) ? wb1 : wb0;
                #pragma unroll
                for (int p = 0; p < 7; ++p) Wn[p] = wbn[p];
            }

            // ---- V: packed 11-tap over ring + SSIM for output row s-10 ----
            if (s >= 10 && s < NROWS) {
                v2f M1=z2, M2=z2, AB=z2, S2=z2;
                #pragma unroll
                for (int k = 0; k < 11; ++k) {
                    const int sl = (j + 1 + k) % 11;   // compile-time
                    M1 = pk_fma2(GV[k], ring_m1[sl], M1);
                    M2 = pk_fma2(GV[k], ring_m2[sl], M2);
                    AB = pk_fma2(GV[k], ring_ab[sl], AB);
                    S2 = pk_fma2(GV[k], ring_s2[sl], S2);
                }
                #pragma unroll
                for (int h = 0; h < 2; ++h) {
                    const float u1 = h ? M1.y : M1.x;
                    const float u2 = h ? M2.y : M2.x;
                    const float eab = h ? AB.y : AB.x;
                    const float es2 = h ? S2.y : S2.x;
                    const float mu12 = u1 * u2;
                    const float musq = fmaf(u1, u1, u2 * u2);
                    const float sig12 = eab - mu12;
                    const float sigsum = fmaxf(fmaf(-2.f, eab, es2) - musq, 0.f);
                    const float num = fmaf(2.f, mu12, K_C1) * fmaf(2.f, sig12, K_C2);
                    const float den = (musq + K_C1) * (sigsum + K_C2);
                    lsum = fmaf(num, __builtin_amdgcn_rcpf(den), lsum);
                }
            }

            // commit prefetched window (register renames in unrolled code)
            #pragma unroll
            for (int p = 0; p < 7; ++p) W[p] = Wn[p];
            cur ^= 1;
        }
    }

    // ---- wave reduce -> one atomic per wave into per-plane slot ----
    #pragma unroll
    for (int off = 32; off > 0; off >>= 1)
        lsum += __shfl_down(lsum, off, 64);
    if (L == 0)
        atomicAdd(&acc[plane], (double)lsum);
}

extern "C" void kernel_launch(void* const* d_in, const int* in_sizes, int n_in,
                              void* d_out, int out_size, void* d_ws, size_t ws_size,
                              hipStream_t stream) {
    const float* img1 = (const float*)d_in[0];
    const float* img2 = (const float*)d_in[1];
    float* out  = (float*)d_out;
    double* acc = (double*)d_ws;   // 96 per-plane accumulators

    ssim_zero<<<dim3(1), dim3(128), 0, stream>>>(acc);
    ssim_main<<<dim3(XS * YB / WPB, PLANES), dim3(64 * WPB), 0, stream>>>(img1, img2, acc);
    ssim_final<<<dim3(1), dim3(64), 0, stream>>>(acc, out);
}